// Round 1
// 105.774 us; speedup vs baseline: 1.0195x; 1.0195x over previous
//
#include <hip/hip_runtime.h>
#include <hip/hip_bf16.h>

#define B_ 4096
#define G_ 8
#define IN_ 512
#define H_ 1024
#define OUT_ 64
#define MAXT64 72   // max 64-row tiles: 4096/64 + 8
#define MAXT32 136  // max 32-row tiles: 4096/32 + 8

typedef float f32x4 __attribute__((ext_vector_type(4)));
typedef __bf16 bf16x8 __attribute__((ext_vector_type(8)));
typedef unsigned short u16x8 __attribute__((ext_vector_type(8)));

__device__ inline unsigned short f2bf(float f) {
  unsigned int u = __builtin_bit_cast(unsigned int, f);
  u += 0x7fffu + ((u >> 16) & 1u);
  return (unsigned short)(u >> 16);
}

__device__ inline u16x8 pack8(float4 a, float4 b) {
  return u16x8{f2bf(a.x), f2bf(a.y), f2bf(a.z), f2bf(a.w),
               f2bf(b.x), f2bf(b.y), f2bf(b.z), f2bf(b.w)};
}

// Async global->LDS DMA, 16 B per lane. LDS dest must be wave-uniform base
// (HW adds lane*16); swizzle is applied on the GLOBAL source address (G21).
// LDS generic->AS3 via 32-bit truncation (shared aperture is 4GB-aligned;
// same trick CK's m0-based direct loads rely on).
__device__ inline void gload16(const void* g, void* l) {
  __builtin_amdgcn_global_load_lds(
      (const __attribute__((address_space(1))) void*)(unsigned long long)g,
      (__attribute__((address_space(3))) void*)(unsigned int)(unsigned long long)l,
      16, 0, 0);
}

// Tile lookup for row-tile size 2^shift.
__device__ inline bool tile_lookup(const int* __restrict__ meta, int mt,
                                   int shift, int& g, int& row0, int& start,
                                   int& cnt) {
  int ts = 0;
  bool found = false;
#pragma unroll
  for (int gg = 0; gg < G_; gg++) {
    int s = meta[gg], e = meta[gg + 1];
    int T = (e - s + (1 << shift) - 1) >> shift;
    if (!found && mt >= ts && mt < ts + T) {
      g = gg;
      row0 = (mt - ts) << shift;
      start = s;
      cnt = e - s;
      found = true;
    }
    ts += T;
  }
  return found;
}

// ---------------------------------------------------------------------------
// prep (fused, all blocks independent):
//   [0,4096):    W1 [G][IN][H] f32 -> W1t [G][H][IN] bf16
//   [4096,4608): W2 [G][H][OUT] f32 -> W2t [G][OUT][H] bf16
//   [4608,5632): x f32 -> xb bf16
//   5632:        deterministic stable bucket (no atomics)
// ---------------------------------------------------------------------------
__global__ __launch_bounds__(256) void prep_kernel(
    const float* __restrict__ W1, const float* __restrict__ W2,
    const float* __restrict__ x, const int* __restrict__ gid,
    unsigned short* __restrict__ W1t, unsigned short* __restrict__ W2t,
    unsigned short* __restrict__ xb, int* __restrict__ meta,
    int* __restrict__ perm) {
  int b = blockIdx.x;
  int t = threadIdx.x;
  if (b < 4096) {
    __shared__ float tile[32][33];
    int h32 = b & 31, k32 = (b >> 5) & 15, g = b >> 9;
    int kl = t >> 3, nl = (t & 7) * 4;
    const float* src =
        W1 + ((size_t)g * IN_ + k32 * 32 + kl) * H_ + h32 * 32 + nl;
    float4 v = *(const float4*)src;
    tile[kl][nl + 0] = v.x;
    tile[kl][nl + 1] = v.y;
    tile[kl][nl + 2] = v.z;
    tile[kl][nl + 3] = v.w;
    __syncthreads();
    int nl2 = t >> 3, kl2 = (t & 7) * 4;
    ushort4 o;
    o.x = f2bf(tile[kl2 + 0][nl2]);
    o.y = f2bf(tile[kl2 + 1][nl2]);
    o.z = f2bf(tile[kl2 + 2][nl2]);
    o.w = f2bf(tile[kl2 + 3][nl2]);
    *(ushort4*)(W1t + ((size_t)g * H_ + h32 * 32 + nl2) * IN_ + k32 * 32 +
                kl2) = o;
  } else if (b < 4608) {
    __shared__ float tile2[32][33];
    int bb = b - 4096;
    int g = bb >> 6, k32 = (bb >> 1) & 31, n32 = bb & 1;
    int kl = t >> 3, nl = (t & 7) * 4;
    const float* src =
        W2 + ((size_t)g * H_ + k32 * 32 + kl) * OUT_ + n32 * 32 + nl;
    float4 v = *(const float4*)src;
    tile2[kl][nl + 0] = v.x;
    tile2[kl][nl + 1] = v.y;
    tile2[kl][nl + 2] = v.z;
    tile2[kl][nl + 3] = v.w;
    __syncthreads();
    int nl2 = t >> 3, kl2 = (t & 7) * 4;
    ushort4 o;
    o.x = f2bf(tile2[kl2 + 0][nl2]);
    o.y = f2bf(tile2[kl2 + 1][nl2]);
    o.z = f2bf(tile2[kl2 + 2][nl2]);
    o.w = f2bf(tile2[kl2 + 3][nl2]);
    *(ushort4*)(W2t + ((size_t)g * OUT_ + n32 * 32 + nl2) * H_ + k32 * 32 +
                kl2) = o;
  } else if (b < 5632) {
    int bb = b - 4608;
    size_t base = (size_t)bb * 2048 + t * 8;
    float4 v0 = *(const float4*)(x + base);
    float4 v1 = *(const float4*)(x + base + 4);
    *(u16x8*)(xb + base) = pack8(v0, v1);
  } else {
    __shared__ unsigned short lc[G_][256];
    __shared__ int offs_s[G_ + 1];
#pragma unroll
    for (int g = 0; g < G_; g++) lc[g][t] = 0;
    int myg[16];
    const int base = t * 16;
    __syncthreads();
#pragma unroll
    for (int j = 0; j < 16; j++) {
      myg[j] = gid[base + j];
      lc[myg[j]][t]++;
    }
    __syncthreads();
    {
      int g = t >> 5, k = t & 31;
      unsigned short pref[8];
      int s = 0;
#pragma unroll
      for (int j = 0; j < 8; j++) {
        pref[j] = (unsigned short)s;
        s += lc[g][8 * k + j];
      }
      int incl = s;
#pragma unroll
      for (int d = 1; d < 32; d <<= 1) {
        int o = __shfl_up(incl, d, 32);
        if (k >= d) incl += o;
      }
      int excl = incl - s;
      if (k == 31) offs_s[g + 1] = incl;
#pragma unroll
      for (int j = 0; j < 8; j++)
        lc[g][8 * k + j] = (unsigned short)(excl + pref[j]);
    }
    __syncthreads();
    if (t == 0) {
      int o = 0;
      for (int g = 0; g < G_; g++) {
        int c = offs_s[g + 1];
        offs_s[g] = o;
        meta[g] = o;
        o += c;
      }
      offs_s[G_] = o;
      meta[G_] = o;
    }
    __syncthreads();
    int cur[G_];
#pragma unroll
    for (int g = 0; g < G_; g++) cur[g] = offs_s[g] + (int)lc[g][t];
#pragma unroll
    for (int j = 0; j < 16; j++) {
      int g = myg[j];
      perm[cur[g]++] = base + j;
    }
  }
}

// ---------------------------------------------------------------------------
// gemm1 (R10): hb[start+r][:] = relu(xb[perm]·W1t[g] + b1[g]), bf16.
// 64x128 tile (576 blocks, 48 KB LDS), BK=64, 8 iters, 4 waves (2x2 of
// 32x64 -> 16 MFMA : 12 ds_read per wave-iter). Staging via global_load_lds
// (width 16) with chunk-XOR swizzle c^(r&7) folded into the per-lane GLOBAL
// source address; LDS dest linear (G21). Double-buffered, 1 barrier/iter.
// ---------------------------------------------------------------------------
__global__ __launch_bounds__(256) void gemm1_kernel(
    const unsigned short* __restrict__ xb,
    const unsigned short* __restrict__ W1t, const float* __restrict__ b1,
    const int* __restrict__ meta, const int* __restrict__ perm,
    unsigned short* __restrict__ hb) {
  int b = blockIdx.x;
  int mt = b >> 3, nt = b & 7;
  int g, row0, start, cnt;
  if (!tile_lookup(meta, mt, 6, g, row0, start, cnt)) return;
  int n0 = nt * 128;

  __shared__ __attribute__((aligned(16))) unsigned short As[2][64 * 64];
  __shared__ __attribute__((aligned(16))) unsigned short Bs[2][128 * 64];
  __shared__ int rows[64];

  int tid = threadIdx.x;
  int lane = tid & 63;
  int wv = tid >> 6;

  if (tid < 64) rows[tid] = perm[start + min(row0 + tid, cnt - 1)];
  __syncthreads();

  // A staging: round j covers LDS shorts [j*2048 + tid*8, +8).
  // LDS row r holds logical chunk (pos ^ (r&7)) at position pos.
  const unsigned short* asrc[2];
#pragma unroll
  for (int j = 0; j < 2; j++) {
    int pp = j * 2048 + tid * 8;
    int r = pp >> 6;          // 0..63, row length 64 shorts
    int cpos = (pp >> 3) & 7;
    asrc[j] = xb + (size_t)rows[r] * IN_ + ((cpos ^ (r & 7)) << 3);
  }
  // B staging: 128 rows x 64 shorts, 4 rounds.
  const unsigned short* bsrc[4];
#pragma unroll
  for (int j = 0; j < 4; j++) {
    int pp = j * 2048 + tid * 8;
    int r = pp >> 6;          // 0..127
    int cpos = (pp >> 3) & 7;
    bsrc[j] = W1t + ((size_t)g * H_ + n0 + r) * IN_ + ((cpos ^ (r & 7)) << 3);
  }

  int fl = lane & 15, q = lane >> 4;
  int wm0 = (wv >> 1) * 32, wn0 = (wv & 1) * 64;

  f32x4 acc[2][4];
#pragma unroll
  for (int i = 0; i < 2; i++)
#pragma unroll
    for (int j = 0; j < 4; j++) acc[i][j] = f32x4{0.f, 0.f, 0.f, 0.f};

  auto stage = [&](int buf, int k0) {
#pragma unroll
    for (int j = 0; j < 2; j++)
      gload16(asrc[j] + k0, &As[buf][j * 2048 + wv * 512]);
#pragma unroll
    for (int j = 0; j < 4; j++)
      gload16(bsrc[j] + k0, &Bs[buf][j * 2048 + wv * 512]);
  };

  stage(0, 0);
  __syncthreads();  // drains vmcnt -> buf0 ready

  for (int it = 0; it < 8; it++) {
    int p = it & 1;
    if (it < 7) stage(p ^ 1, (it + 1) * 64);  // in flight over compute
#pragma unroll
    for (int s = 0; s < 2; s++) {
      int off = (((s << 2) + q) ^ (fl & 7)) << 3;
      bf16x8 a0 = *(const bf16x8*)&As[p][(wm0 + fl) * 64 + off];
      bf16x8 a1 = *(const bf16x8*)&As[p][(wm0 + 16 + fl) * 64 + off];
      bf16x8 b0 = *(const bf16x8*)&Bs[p][(wn0 + fl) * 64 + off];
      bf16x8 b1v = *(const bf16x8*)&Bs[p][(wn0 + 16 + fl) * 64 + off];
      bf16x8 b2v = *(const bf16x8*)&Bs[p][(wn0 + 32 + fl) * 64 + off];
      bf16x8 b3v = *(const bf16x8*)&Bs[p][(wn0 + 48 + fl) * 64 + off];
      acc[0][0] = __builtin_amdgcn_mfma_f32_16x16x32_bf16(a0, b0, acc[0][0], 0, 0, 0);
      acc[0][1] = __builtin_amdgcn_mfma_f32_16x16x32_bf16(a0, b1v, acc[0][1], 0, 0, 0);
      acc[0][2] = __builtin_amdgcn_mfma_f32_16x16x32_bf16(a0, b2v, acc[0][2], 0, 0, 0);
      acc[0][3] = __builtin_amdgcn_mfma_f32_16x16x32_bf16(a0, b3v, acc[0][3], 0, 0, 0);
      acc[1][0] = __builtin_amdgcn_mfma_f32_16x16x32_bf16(a1, b0, acc[1][0], 0, 0, 0);
      acc[1][1] = __builtin_amdgcn_mfma_f32_16x16x32_bf16(a1, b1v, acc[1][1], 0, 0, 0);
      acc[1][2] = __builtin_amdgcn_mfma_f32_16x16x32_bf16(a1, b2v, acc[1][2], 0, 0, 0);
      acc[1][3] = __builtin_amdgcn_mfma_f32_16x16x32_bf16(a1, b3v, acc[1][3], 0, 0, 0);
    }
    __syncthreads();  // one barrier/iter: drains next-tile DMA + frees buf p
  }

#pragma unroll
  for (int ni = 0; ni < 4; ni++) {
    int col = n0 + wn0 + ni * 16 + fl;
    float bias = b1[g * H_ + col];
#pragma unroll
    for (int mi = 0; mi < 2; mi++) {
#pragma unroll
      for (int rg = 0; rg < 4; rg++) {
        int rl = wm0 + mi * 16 + q * 4 + rg;
        if (row0 + rl < cnt) {
          float v = fmaxf(acc[mi][ni][rg] + bias, 0.f);
          hb[(size_t)(start + row0 + rl) * H_ + col] = f2bf(v);
        }
      }
    }
  }
}

// ---------------------------------------------------------------------------
// gemm2 (R10): y[perm[r]] = hb[r]·W2t[g] + b2[g]. 32x64 tile (136 blocks,
// 1.9x CU coverage vs 64-row), BK=128 (8 iters), 4 waves (2x2 of 16x32),
// global_load_lds staging, double-buffered, plain stores, deterministic.
// ---------------------------------------------------------------------------
__global__ __launch_bounds__(256) void gemm2_kernel(
    const unsigned short* __restrict__ hb,
    const unsigned short* __restrict__ W2t, const float* __restrict__ b2,
    const int* __restrict__ meta, const int* __restrict__ perm,
    float* __restrict__ y) {
  int mt = blockIdx.x;
  int g, row0, start, cnt;
  if (!tile_lookup(meta, mt, 5, g, row0, start, cnt)) return;

  __shared__ __attribute__((aligned(16))) unsigned short As2[2][32 * 128];
  __shared__ __attribute__((aligned(16))) unsigned short Bs2[2][64 * 128];
  __shared__ int rows[32];

  int tid = threadIdx.x;
  int lane = tid & 63;
  int wv = tid >> 6;

  if (tid < 32) rows[tid] = perm[start + min(row0 + tid, cnt - 1)];
  // rows[] only read in the epilogue (after >=2 barriers); A staging
  // addresses hb by permuted-order index directly.

  const unsigned short* asrc[2];
#pragma unroll
  for (int j = 0; j < 2; j++) {
    int pp = j * 2048 + tid * 8;
    int r = pp >> 7;           // 0..31, row length 128 shorts
    int cpos = (pp >> 3) & 15;
    asrc[j] = hb + (size_t)(start + min(row0 + r, cnt - 1)) * H_ +
              ((cpos ^ (r & 7)) << 3);
  }
  const unsigned short* bsrc[4];
#pragma unroll
  for (int j = 0; j < 4; j++) {
    int pp = j * 2048 + tid * 8;
    int r = pp >> 7;           // 0..63
    int cpos = (pp >> 3) & 15;
    bsrc[j] = W2t + ((size_t)g * OUT_ + r) * H_ + ((cpos ^ (r & 7)) << 3);
  }

  int fl = lane & 15, q = lane >> 4;
  int wm0 = (wv >> 1) * 16, wn0 = (wv & 1) * 32;

  f32x4 acc[2];
  acc[0] = f32x4{0.f, 0.f, 0.f, 0.f};
  acc[1] = f32x4{0.f, 0.f, 0.f, 0.f};

  auto stage = [&](int buf, int k0) {
#pragma unroll
    for (int j = 0; j < 2; j++)
      gload16(asrc[j] + k0, &As2[buf][j * 2048 + wv * 512]);
#pragma unroll
    for (int j = 0; j < 4; j++)
      gload16(bsrc[j] + k0, &Bs2[buf][j * 2048 + wv * 512]);
  };

  stage(0, 0);
  __syncthreads();

  for (int it = 0; it < 8; it++) {
    int p = it & 1;
    if (it < 7) stage(p ^ 1, (it + 1) * 128);
#pragma unroll
    for (int s = 0; s < 4; s++) {
      int off = (((s << 2) + q) ^ (fl & 7)) << 3;
      bf16x8 a0 = *(const bf16x8*)&As2[p][(wm0 + fl) * 128 + off];
      bf16x8 b0 = *(const bf16x8*)&Bs2[p][(wn0 + fl) * 128 + off];
      bf16x8 b1v = *(const bf16x8*)&Bs2[p][(wn0 + 16 + fl) * 128 + off];
      acc[0] = __builtin_amdgcn_mfma_f32_16x16x32_bf16(a0, b0, acc[0], 0, 0, 0);
      acc[1] = __builtin_amdgcn_mfma_f32_16x16x32_bf16(a0, b1v, acc[1], 0, 0, 0);
    }
    __syncthreads();
  }

#pragma unroll
  for (int ni = 0; ni < 2; ni++) {
    int col = wn0 + ni * 16 + fl;
    float bias = b2[g * OUT_ + col];
#pragma unroll
    for (int rg = 0; rg < 4; rg++) {
      int rl = wm0 + q * 4 + rg;
      if (row0 + rl < cnt) {
        y[(size_t)rows[rl] * OUT_ + col] = acc[ni][rg] + bias;
      }
    }
  }
}

extern "C" void kernel_launch(void* const* d_in, const int* in_sizes, int n_in,
                              void* d_out, int out_size, void* d_ws,
                              size_t ws_size, hipStream_t stream) {
  const float* x = (const float*)d_in[0];
  const int* gid = (const int*)d_in[1];
  const float* W1 = (const float*)d_in[2];
  const float* b1 = (const float*)d_in[3];
  const float* W2 = (const float*)d_in[4];
  const float* b2 = (const float*)d_in[5];
  float* y = (float*)d_out;

  int* meta = (int*)d_ws;                                             // 64 B
  int* perm = (int*)((char*)d_ws + 64);                               // 16 KB
  unsigned short* W1t = (unsigned short*)((char*)d_ws + (1u << 16));  // 8 MB
  unsigned short* W2t = (unsigned short*)((char*)d_ws + (16u << 20)); // 1 MB
  unsigned short* xb = (unsigned short*)((char*)d_ws + (24u << 20));  // 4 MB
  unsigned short* hb = (unsigned short*)((char*)d_ws + (32u << 20));  // 8 MB

  prep_kernel<<<5633, 256, 0, stream>>>(W1, W2, x, gid, W1t, W2t, xb, meta,
                                        perm);
  gemm1_kernel<<<MAXT64 * 8, 256, 0, stream>>>(xb, W1t, b1, meta, perm, hb);
  gemm2_kernel<<<MAXT32, 256, 0, stream>>>(hb, W2t, b2, meta, perm, y);
}